// Round 5
// baseline (125.175 us; speedup 1.0000x reference)
//
#include <hip/hip_runtime.h>
#include <math.h>

// Problem constants (match reference)
#define BB 64
#define DD 1024
#define GG 64
#define F4 (DD / 4)        // 256 float4 per row
#define ROWS 4             // u-rows per wave
#define WAVES_PB 4         // waves per block
#define U_PER_BLOCK (ROWS * WAVES_PB)          // 16
#define BLOCKS_PER_B (DD / U_PER_BLOCK)        // 64
#define NWG (BB * BLOCKS_PER_B)                // 4096

__device__ __forceinline__ float softplus_fast(float z) {
    // softplus(z) = max(z,0) + ln2 * log2(1 + exp(-|z|))
    const float LOG2E = 1.44269504088896340736f;
    const float LN2   = 0.69314718055994530942f;
    float t = __builtin_amdgcn_exp2f(-LOG2E * fabsf(z));   // exp(-|z|)
    float l = __builtin_amdgcn_logf(1.0f + t);             // log2(1+t), v_log_f32
    return fmaxf(z, 0.0f) + LN2 * l;
}

__global__ __launch_bounds__(256) void mld_kernel(
    const float* __restrict__ x, const int* __restrict__ gid,
    const float* __restrict__ w_mu, const float* __restrict__ w_sigma,
    const float* __restrict__ b_mu, const float* __restrict__ b_sigma,
    const float* __restrict__ eps_w, const float* __restrict__ eps_b,
    float* __restrict__ out)
{
    const int lane = (int)(threadIdx.x & 63);
    const int wid  = (int)(threadIdx.x >> 6);          // 0..3

    // XCD-chunked bijective swizzle (NWG = 4096, divisible by 8):
    // hardware round-robins blockIdx across 8 XCDs; this makes each XCD
    // own a contiguous chunk of logical blocks (= 8 consecutive samples),
    // so the gathered w_mu/w_sigma rows are fetched by ~1 XCD, not 8.
    const int bid     = (int)blockIdx.x;
    const int logical = (bid & 7) * (NWG >> 3) + (bid >> 3);

    const int b    = logical >> 6;                     // BLOCKS_PER_B = 64
    const int ublk = logical & 63;
    const int u0   = ublk * U_PER_BLOCK + wid * ROWS;  // wave's first u row
    const int g    = gid[b];

    const float4* __restrict__ xr  = (const float4*)(x + (size_t)b * DD);
    const float4* __restrict__ wmr = (const float4*)(w_mu    + ((size_t)g * DD + u0) * DD);
    const float4* __restrict__ wsr = (const float4*)(w_sigma + ((size_t)g * DD + u0) * DD);
    const float4* __restrict__ ewr = (const float4*)(eps_w   + ((size_t)b * DD + u0) * DD);

    float acc[ROWS] = {0.f, 0.f, 0.f, 0.f};

    #pragma unroll
    for (int k = 0; k < 4; ++k) {
        const int i = lane + k * 64;                   // 256 float4 per row
        const float4 xm = xr[i];
        #pragma unroll
        for (int r = 0; r < ROWS; ++r) {
            const int j = r * F4 + i;
            const float4 wm = wmr[j];
            const float4 ws = wsr[j];
            const float4 ew = ewr[j];
            float a = acc[r];
            a += (wm.x + softplus_fast(ws.x) * ew.x) * xm.x;
            a += (wm.y + softplus_fast(ws.y) * ew.y) * xm.y;
            a += (wm.z + softplus_fast(ws.z) * ew.z) * xm.z;
            a += (wm.w + softplus_fast(ws.w) * ew.w) * xm.w;
            acc[r] = a;
        }
    }

    // 4 independent butterfly reductions (all lanes end with the row sums)
    #pragma unroll
    for (int off = 32; off > 0; off >>= 1) {
        #pragma unroll
        for (int r = 0; r < ROWS; ++r)
            acc[r] += __shfl_xor(acc[r], off, 64);
    }

    // lanes 0..3 each handle one row's bias + relu + store (parallel epilogue)
    if (lane < ROWS) {
        const int u = u0 + lane;
        const size_t gu = (size_t)g * DD + u;
        const size_t bu = (size_t)b * DD + u;
        const float bs = b_mu[gu] + softplus_fast(b_sigma[gu]) * eps_b[bu];
        const float o = acc[lane] + bs;
        out[bu] = fmaxf(o, 0.0f);
    }
}

extern "C" void kernel_launch(void* const* d_in, const int* in_sizes, int n_in,
                              void* d_out, int out_size, void* d_ws, size_t ws_size,
                              hipStream_t stream) {
    const float* x       = (const float*)d_in[0];
    const int*   gid     = (const int*)d_in[1];
    const float* w_mu    = (const float*)d_in[2];
    const float* w_sigma = (const float*)d_in[3];
    const float* b_mu    = (const float*)d_in[4];
    const float* b_sigma = (const float*)d_in[5];
    const float* eps_w   = (const float*)d_in[6];
    const float* eps_b   = (const float*)d_in[7];
    float* out = (float*)d_out;

    mld_kernel<<<NWG, 256, 0, stream>>>(x, gid, w_mu, w_sigma, b_mu, b_sigma,
                                        eps_w, eps_b, out);
}

// Round 7
// 112.946 us; speedup vs baseline: 1.1083x; 1.1083x over previous
//
#include <hip/hip_runtime.h>
#include <math.h>

// Problem constants (match reference)
#define BB 64
#define DD 1024
#define GG 64
#define F4 (DD / 4)        // 256 float4 per row
#define ROWS 2             // u-rows per wave
#define WAVES_PB 4         // waves per block
#define U_PER_BLOCK (ROWS * WAVES_PB)          // 8
#define BLOCKS_PER_B (DD / U_PER_BLOCK)        // 128
#define NWG (BB * BLOCKS_PER_B)                // 8192

typedef float fvec4 __attribute__((ext_vector_type(4)));   // native vector for nt-load

__device__ __forceinline__ float softplus_fast(float z) {
    // softplus(z) = max(z,0) + ln2 * log2(1 + exp(-|z|))
    const float LOG2E = 1.44269504088896340736f;
    const float LN2   = 0.69314718055994530942f;
    float t = __builtin_amdgcn_exp2f(-LOG2E * fabsf(z));   // exp(-|z|)
    float l = __builtin_amdgcn_logf(1.0f + t);             // log2(1+t), v_log_f32
    return fmaxf(z, 0.0f) + LN2 * l;
}

__device__ __forceinline__ fvec4 nt_load4(const float* p) {
    return __builtin_nontemporal_load((const fvec4*)p);
}

__global__ __launch_bounds__(256) void mld_kernel(
    const float* __restrict__ x, const int* __restrict__ gid,
    const float* __restrict__ w_mu, const float* __restrict__ w_sigma,
    const float* __restrict__ b_mu, const float* __restrict__ b_sigma,
    const float* __restrict__ eps_w, const float* __restrict__ eps_b,
    float* __restrict__ out)
{
    const int lane = (int)(threadIdx.x & 63);
    const int wid  = (int)(threadIdx.x >> 6);          // 0..3

    // Natural block order: block n -> XCD n%8. Since BLOCKS_PER_B % 8 == 0,
    // same-u blocks of samples sharing a group land on the SAME XCD -> their
    // w_mu/w_sigma rows are shared in that XCD's L2. (Round-5 swizzle broke
    // this and regressed; do not reorder blocks.)
    const int logical = (int)blockIdx.x;
    const int b    = logical >> 7;                     // BLOCKS_PER_B = 128
    const int ublk = logical & 127;
    const int u0   = ublk * U_PER_BLOCK + wid * ROWS;  // wave's first u row
    const int g    = gid[b];

    const float4* __restrict__ xr  = (const float4*)(x + (size_t)b * DD);
    const float4* __restrict__ wmr = (const float4*)(w_mu    + ((size_t)g * DD + u0) * DD);
    const float4* __restrict__ wsr = (const float4*)(w_sigma + ((size_t)g * DD + u0) * DD);
    const float*  __restrict__ ewr = eps_w + ((size_t)b * DD + u0) * DD;

    float acc[ROWS] = {0.f, 0.f};

    #pragma unroll
    for (int k = 0; k < 4; ++k) {
        const int i = lane + k * 64;                   // 256 float4 per row
        const float4 xm = xr[i];
        #pragma unroll
        for (int r = 0; r < ROWS; ++r) {
            const int j = r * F4 + i;
            const float4 wm = wmr[j];
            const float4 ws = wsr[j];
            const fvec4  ew = nt_load4(ewr + 4 * (size_t)j);  // once-only stream
            float a = acc[r];
            a += (wm.x + softplus_fast(ws.x) * ew.x) * xm.x;
            a += (wm.y + softplus_fast(ws.y) * ew.y) * xm.y;
            a += (wm.z + softplus_fast(ws.z) * ew.z) * xm.z;
            a += (wm.w + softplus_fast(ws.w) * ew.w) * xm.w;
            acc[r] = a;
        }
    }

    // 2 independent butterfly reductions (all lanes end with the row sums)
    #pragma unroll
    for (int off = 32; off > 0; off >>= 1) {
        #pragma unroll
        for (int r = 0; r < ROWS; ++r)
            acc[r] += __shfl_xor(acc[r], off, 64);
    }

    // lanes 0..1 each handle one row's bias + relu + store
    if (lane < ROWS) {
        const int u = u0 + lane;
        const size_t gu = (size_t)g * DD + u;
        const size_t bu = (size_t)b * DD + u;
        const float eb = __builtin_nontemporal_load(eps_b + bu);
        const float bs = b_mu[gu] + softplus_fast(b_sigma[gu]) * eb;
        const float o = acc[lane] + bs;
        out[bu] = fmaxf(o, 0.0f);
    }
}

extern "C" void kernel_launch(void* const* d_in, const int* in_sizes, int n_in,
                              void* d_out, int out_size, void* d_ws, size_t ws_size,
                              hipStream_t stream) {
    const float* x       = (const float*)d_in[0];
    const int*   gid     = (const int*)d_in[1];
    const float* w_mu    = (const float*)d_in[2];
    const float* w_sigma = (const float*)d_in[3];
    const float* b_mu    = (const float*)d_in[4];
    const float* b_sigma = (const float*)d_in[5];
    const float* eps_w   = (const float*)d_in[6];
    const float* eps_b   = (const float*)d_in[7];
    float* out = (float*)d_out;

    mld_kernel<<<NWG, 256, 0, stream>>>(x, gid, w_mu, w_sigma, b_mu, b_sigma,
                                        eps_w, eps_b, out);
}

// Round 8
// 112.046 us; speedup vs baseline: 1.1172x; 1.0080x over previous
//
#include <hip/hip_runtime.h>
#include <math.h>

// Problem constants (match reference)
#define BB 64
#define DD 1024
#define GG 64
#define F4 (DD / 4)        // 256 float4 per row
#define ROWS 2             // u-rows per wave
#define WAVES_PB 4         // waves per block
#define U_PER_BLOCK (ROWS * WAVES_PB)          // 8
#define BLOCKS_PER_B (DD / U_PER_BLOCK)        // 128
#define NWG (BB * BLOCKS_PER_B)                // 8192

typedef float fvec4 __attribute__((ext_vector_type(4)));

__device__ __forceinline__ float softplus_fast(float z) {
    // softplus(z) = max(z,0) + ln2 * log2(1 + exp(-|z|))
    const float LOG2E = 1.44269504088896340736f;
    const float LN2   = 0.69314718055994530942f;
    float t = __builtin_amdgcn_exp2f(-LOG2E * fabsf(z));   // v_exp_f32
    float l = __builtin_amdgcn_logf(1.0f + t);             // v_log_f32 (log2)
    return fmaxf(z, 0.0f) + LN2 * l;
}

// One k-step of data for 2 rows: 7 independent float4 loads (7 KB/wave).
struct Batch { fvec4 xm, wm0, ws0, ew0, wm1, ws1, ew1; };

__device__ __forceinline__ Batch load_batch(const fvec4* __restrict__ xr,
                                            const fvec4* __restrict__ wmr,
                                            const fvec4* __restrict__ wsr,
                                            const fvec4* __restrict__ ewr,
                                            int i) {
    Batch t;
    t.xm  = xr[i];
    t.wm0 = wmr[i];
    t.ws0 = wsr[i];
    t.ew0 = __builtin_nontemporal_load(ewr + i);        // once-only stream
    t.wm1 = wmr[F4 + i];
    t.ws1 = wsr[F4 + i];
    t.ew1 = __builtin_nontemporal_load(ewr + F4 + i);
    return t;
}

__device__ __forceinline__ void consume(const Batch& t, float& a0, float& a1) {
    a0 += (t.wm0.x + softplus_fast(t.ws0.x) * t.ew0.x) * t.xm.x;
    a0 += (t.wm0.y + softplus_fast(t.ws0.y) * t.ew0.y) * t.xm.y;
    a0 += (t.wm0.z + softplus_fast(t.ws0.z) * t.ew0.z) * t.xm.z;
    a0 += (t.wm0.w + softplus_fast(t.ws0.w) * t.ew0.w) * t.xm.w;
    a1 += (t.wm1.x + softplus_fast(t.ws1.x) * t.ew1.x) * t.xm.x;
    a1 += (t.wm1.y + softplus_fast(t.ws1.y) * t.ew1.y) * t.xm.y;
    a1 += (t.wm1.z + softplus_fast(t.ws1.z) * t.ew1.z) * t.xm.z;
    a1 += (t.wm1.w + softplus_fast(t.ws1.w) * t.ew1.w) * t.xm.w;
}

// (256, 4): allow up to 128 VGPRs so the 2-deep load pipeline stays in flight.
__global__ __launch_bounds__(256, 4) void mld_kernel(
    const float* __restrict__ x, const int* __restrict__ gid,
    const float* __restrict__ w_mu, const float* __restrict__ w_sigma,
    const float* __restrict__ b_mu, const float* __restrict__ b_sigma,
    const float* __restrict__ eps_w, const float* __restrict__ eps_b,
    float* __restrict__ out)
{
    const int lane = (int)(threadIdx.x & 63);
    const int wid  = (int)(threadIdx.x >> 6);          // 0..3

    // Natural block order (round-5 swizzle regressed; keep hardware mapping).
    const int logical = (int)blockIdx.x;
    const int b    = logical >> 7;                     // BLOCKS_PER_B = 128
    const int ublk = logical & 127;
    const int u0   = ublk * U_PER_BLOCK + wid * ROWS;  // wave's first u row
    const int g    = gid[b];

    const fvec4* __restrict__ xr  = (const fvec4*)(x + (size_t)b * DD);
    const fvec4* __restrict__ wmr = (const fvec4*)(w_mu    + ((size_t)g * DD + u0) * DD);
    const fvec4* __restrict__ wsr = (const fvec4*)(w_sigma + ((size_t)g * DD + u0) * DD);
    const fvec4* __restrict__ ewr = (const fvec4*)(eps_w   + ((size_t)b * DD + u0) * DD);

    float a0 = 0.f, a1 = 0.f;

    // 2-deep software pipeline over the 4 k-steps: issue k+1 before consuming k.
    Batch A = load_batch(xr, wmr, wsr, ewr, lane);            // k=0
    Batch B = load_batch(xr, wmr, wsr, ewr, lane + 64);       // k=1
    consume(A, a0, a1);
    A = load_batch(xr, wmr, wsr, ewr, lane + 128);            // k=2
    consume(B, a0, a1);
    B = load_batch(xr, wmr, wsr, ewr, lane + 192);            // k=3
    consume(A, a0, a1);
    consume(B, a0, a1);

    // 2 independent butterfly reductions (all lanes end with the row sums)
    #pragma unroll
    for (int off = 32; off > 0; off >>= 1) {
        a0 += __shfl_xor(a0, off, 64);
        a1 += __shfl_xor(a1, off, 64);
    }

    // lanes 0..1 each handle one row's bias + relu + store
    if (lane < ROWS) {
        const int u = u0 + lane;
        const size_t gu = (size_t)g * DD + u;
        const size_t bu = (size_t)b * DD + u;
        const float eb = __builtin_nontemporal_load(eps_b + bu);
        const float bs = b_mu[gu] + softplus_fast(b_sigma[gu]) * eb;
        const float o = (lane == 0 ? a0 : a1) + bs;
        out[bu] = fmaxf(o, 0.0f);
    }
}

extern "C" void kernel_launch(void* const* d_in, const int* in_sizes, int n_in,
                              void* d_out, int out_size, void* d_ws, size_t ws_size,
                              hipStream_t stream) {
    const float* x       = (const float*)d_in[0];
    const int*   gid     = (const int*)d_in[1];
    const float* w_mu    = (const float*)d_in[2];
    const float* w_sigma = (const float*)d_in[3];
    const float* b_mu    = (const float*)d_in[4];
    const float* b_sigma = (const float*)d_in[5];
    const float* eps_w   = (const float*)d_in[6];
    const float* eps_b   = (const float*)d_in[7];
    float* out = (float*)d_out;

    mld_kernel<<<NWG, 256, 0, stream>>>(x, gid, w_mu, w_sigma, b_mu, b_sigma,
                                        eps_w, eps_b, out);
}